// Round 11
// baseline (346.761 us; speedup 1.0000x reference)
//
#include <hip/hip_runtime.h>
#include <hip/hip_fp16.h>

#define N_FEAT0 128
#define HID 64
#define NCLS 40

#define BSH 9            // log2 nodes per bucket
#define BSZ 512          // nodes per bucket
#define BCAP 12288       // slab capacity per bucket (mean 8192, sigma ~90 -> 45 sigma margin)
#define STILE 4096       // edges per scatter block (391 blocks)

typedef _Float16 half8 __attribute__((ext_vector_type(8)));
typedef float f32x4 __attribute__((ext_vector_type(4)));

// ---------------- phase 1: LDS-binned scatter of edges into per-bucket slabs ----
// Record = (d & 511) << 17 | s   (s < 2^17 since N = 100000 < 131072).
// Round-11: edges register-staged across both passes (no pass-B re-read).
__global__ __launch_bounds__(256) void scatter_kernel(const int* __restrict__ esrc,
                                                      const int* __restrict__ edst,
                                                      int* __restrict__ bfill,
                                                      int* __restrict__ slab, int E) {
  __shared__ int cnt[256];
  __shared__ int base[256];
  int t = threadIdx.x;
  int t0 = blockIdx.x * STILE;
  cnt[t] = 0;
  __syncthreads();

  int4 s4[4], d4[4];
  bool ok[4];
  // pass A: load into registers + bucket histogram (E % 4 == 0 -> int4 safe)
#pragma unroll
  for (int i = 0; i < 4; ++i) {
    int e = t0 + i * 1024 + t * 4;
    ok[i] = (e < E);
    if (ok[i]) {
      s4[i] = *(const int4*)(esrc + e);
      d4[i] = *(const int4*)(edst + e);
      atomicAdd(&cnt[d4[i].x >> BSH], 1);
      atomicAdd(&cnt[d4[i].y >> BSH], 1);
      atomicAdd(&cnt[d4[i].z >> BSH], 1);
      atomicAdd(&cnt[d4[i].w >> BSH], 1);
    }
  }
  __syncthreads();
  int c = cnt[t];
  if (c > 0) base[t] = t * BCAP + atomicAdd(&bfill[t], c);
  cnt[t] = 0;
  __syncthreads();

  // pass B: binned emit from registers
#pragma unroll
  for (int i = 0; i < 4; ++i) {
    if (ok[i]) {
#define EMIT(dd, ss)                                             \
      {                                                          \
        int b_ = (dd) >> BSH;                                    \
        int r_ = atomicAdd(&cnt[b_], 1);                         \
        slab[base[b_] + r_] = (((dd) & (BSZ - 1)) << 17) | (ss); \
      }
      EMIT(d4[i].x, s4[i].x)
      EMIT(d4[i].y, s4[i].y)
      EMIT(d4[i].z, s4[i].z)
      EMIT(d4[i].w, s4[i].w)
#undef EMIT
    }
  }
}

// ---------------- phase 2a: per-node histogram (4 blocks per bucket) ----------
// LDS histogram of the sub-block's record range, flushed with one global
// atomicAdd per nonzero node counter (distinct addresses -> no hot contention).
__global__ __launch_bounds__(256) void hist_kernel(const int* __restrict__ slab,
                                                   const int* __restrict__ bfill,
                                                   int* __restrict__ counts, int N) {
  __shared__ int h[512];
  int b = blockIdx.x >> 2;
  int q = blockIdx.x & 3;
  int t = threadIdx.x;
  h[t] = 0;
  h[t + 256] = 0;
  __syncthreads();
  int sz = bfill[b];
  int sbeg = b * BCAP;
  int r0 = (int)(((long long)sz * q) >> 2);
  int r1 = (int)(((long long)sz * (q + 1)) >> 2);
  for (int r = r0 + t; r < r1; r += 256)
    atomicAdd(&h[((unsigned)slab[sbeg + r]) >> 17], 1);
  __syncthreads();
  int nbase = b << BSH;
  if (nbase + t < N && h[t]) atomicAdd(&counts[nbase + t], h[t]);
  int t2 = t + 256;
  if (nbase + t2 < N && h[t2]) atomicAdd(&counts[nbase + t2], h[t2]);
}

// ---------------- phase 2b: row_ptr + dinv (bucket-base scan + node scan) -----
__global__ __launch_bounds__(512) void scan_kernel(const int* __restrict__ bfill,
                                                   const int* __restrict__ counts,
                                                   int* __restrict__ row_ptr,
                                                   float* __restrict__ dinv,
                                                   int N, int nbuck) {
  __shared__ int sc[256];
  __shared__ int pre[512];
  int b = blockIdx.x;
  int t = threadIdx.x;
  if (t < 256) sc[t] = (t < nbuck) ? bfill[t] : 0;
  __syncthreads();
  for (int off = 1; off < 256; off <<= 1) {
    int u = 0;
    if (t < 256 && t >= off) u = sc[t - off];
    __syncthreads();
    if (t < 256) sc[t] += u;
    __syncthreads();
  }
  int obase = sc[b] - bfill[b];
  if (b == 0 && t == 0) row_ptr[N] = sc[255];  // total == E
  int nbase = b << BSH;
  int nNodes = N - nbase;
  if (nNodes > BSZ) nNodes = BSZ;
  int c = (t < nNodes) ? counts[nbase + t] : 0;
  pre[t] = c;
  __syncthreads();
  for (int off = 1; off < 512; off <<= 1) {
    int u = (t >= off) ? pre[t - off] : 0;
    __syncthreads();
    pre[t] += u;
    __syncthreads();
  }
  if (t < nNodes) {
    row_ptr[nbase + t] = obase + pre[t] - c;
    dinv[nbase + t] = rsqrtf((float)(c + 1));
  }
}

// ---------------- phase 2c: permute into node-ordered ew (4 blocks/bucket) ----
// Rank via global atomicSub on counts (L2-local, consumed to zero -> no fillc).
__global__ __launch_bounds__(256) void perm_kernel(const int* __restrict__ slab,
                                                   const int* __restrict__ bfill,
                                                   const int* __restrict__ row_ptr,
                                                   int* __restrict__ counts,
                                                   int* __restrict__ ew, int N) {
  __shared__ int rp[512];
  int b = blockIdx.x >> 2;
  int q = blockIdx.x & 3;
  int t = threadIdx.x;
  int nbase = b << BSH;
  int nNodes = N - nbase;
  if (nNodes > BSZ) nNodes = BSZ;
  if (t < nNodes) rp[t] = row_ptr[nbase + t];
  int t2 = t + 256;
  if (t2 < nNodes) rp[t2] = row_ptr[nbase + t2];
  __syncthreads();
  int sz = bfill[b];
  int sbeg = b * BCAP;
  int r0 = (int)(((long long)sz * q) >> 2);
  int r1 = (int)(((long long)sz * (q + 1)) >> 2);
  for (int r = r0 + t; r < r1; r += 256) {
    int rec = slab[sbeg + r];
    int dloc = ((unsigned)rec) >> 17;
    int rank = atomicSub(&counts[nbase + dloc], 1) - 1;
    ew[rp[dloc] + rank] = rec & 0x1FFFF;
  }
}

// ---------------- W prep: transpose + fp16-convert the three weight matrices ----
__global__ __launch_bounds__(256) void prep_w_kernel(const float* __restrict__ W0,
                                                     const float* __restrict__ W1,
                                                     const float* __restrict__ W2,
                                                     __half* __restrict__ Wt0,
                                                     __half* __restrict__ Wt1,
                                                     __half* __restrict__ Wt2) {
  int id = blockIdx.x * 256 + threadIdx.x;
  if (id < 8192) {                       // Wt0: 64 x 128
    int c = id >> 7, k = id & 127;
    Wt0[id] = __float2half_rn(W0[k * 64 + c]);
  } else if (id < 8192 + 4096) {         // Wt1: 64 x 64
    int i = id - 8192;
    int c = i >> 6, k = i & 63;
    Wt1[i] = __float2half_rn(W1[k * 64 + c]);
  } else if (id < 8192 + 4096 + 3072) {  // Wt2: 48 x 64 (cols 40..47 zero)
    int i = id - 8192 - 4096;
    int c = i >> 6, k = i & 63;
    Wt2[i] = (c < NCLS) ? __float2half_rn(W2[k * NCLS + c]) : __half(0.f);
  }
}

// ---------------- MFMA GEMM: Out[r][c] = (half) dinv[r] * sum_k A[r][k] W[k][c] --
// v_mfma_f32_16x16x32_f16, verified layouts (guide m89/m91). One wave = one
// 16-row x NC tile; no LDS, no barriers.
template <int K, int NC, bool AF32>
__global__ __launch_bounds__(256) void gemm_mfma(const void* __restrict__ Av,
                                                 const __half* __restrict__ Wt,
                                                 __half* __restrict__ Out,
                                                 const float* __restrict__ dinv,
                                                 int N) {
  constexpr int NT = (NC + 15) / 16;
  int lane = threadIdx.x & 63;
  int r16 = lane & 15;
  int kq = lane >> 4;
  int wid = blockIdx.x * 4 + (threadIdx.x >> 6);
  int ntiles = (N + 15) >> 4;
  if (wid >= ntiles) return;
  int r0 = wid << 4;

  const __half* Ah = (const __half*)Av;
  const float* Af = (const float*)Av;
  int arow = r0 + r16;
  if (arow >= N) arow = N - 1;

  f32x4 acc[NT];
#pragma unroll
  for (int t2 = 0; t2 < NT; ++t2) acc[t2] = (f32x4){0.f, 0.f, 0.f, 0.f};

#pragma unroll
  for (int s = 0; s < K / 32; ++s) {
    half8 a;
    if constexpr (AF32) {
      const float* ap = Af + (size_t)arow * K + s * 32 + kq * 8;
      float4 v0 = *(const float4*)ap;
      float4 v1 = *(const float4*)(ap + 4);
      a[0] = (_Float16)v0.x; a[1] = (_Float16)v0.y;
      a[2] = (_Float16)v0.z; a[3] = (_Float16)v0.w;
      a[4] = (_Float16)v1.x; a[5] = (_Float16)v1.y;
      a[6] = (_Float16)v1.z; a[7] = (_Float16)v1.w;
    } else {
      a = *(const half8*)(Ah + (size_t)arow * K + s * 32 + kq * 8);
    }
#pragma unroll
    for (int t2 = 0; t2 < NT; ++t2) {
      half8 b = *(const half8*)(Wt + (size_t)(t2 * 16 + r16) * K + s * 32 + kq * 8);
      acc[t2] = __builtin_amdgcn_mfma_f32_16x16x32_f16(a, b, acc[t2], 0, 0, 0);
    }
  }

  float4 dv = *(const float4*)(dinv + r0 + kq * 4);
  float ds[4] = {dv.x, dv.y, dv.z, dv.w};
#pragma unroll
  for (int b = 0; b < 4; ++b) {
    int gr = r0 + kq * 4 + b;
#pragma unroll
    for (int t2 = 0; t2 < NT; ++t2) {
      int col = t2 * 16 + r16;
      if (col < NC) Out[(size_t)gr * NC + col] = __float2half_rn(ds[b] * acc[t2][b]);
    }
  }
}

// ---------------- sparse aggregation: one wave per node, fp16 gather ---------
// Row-major G: one edge = one 128B line request (line-rate optimal; round-7
// planar proved line-request count, not bytes, is the wall).
template <int F, bool HOUT>
__global__ __launch_bounds__(256) void agg_kernel(const __half* __restrict__ G,
                                                  const int* __restrict__ row_ptr,
                                                  const int* __restrict__ ew,
                                                  const float* __restrict__ dinv,
                                                  void* __restrict__ HoutV, int N) {
  constexpr int FO = F / 8;
  int gid = blockIdx.x * blockDim.x + threadIdx.x;
  int v = gid >> 6;
  if (v >= N) return;
  int lane = threadIdx.x & 63;
  int eg = lane >> 3;
  int fo = lane & 7;
  bool fok = (fo < FO);
  int foc = fok ? fo : FO - 1;

  float acc[8];
#pragma unroll
  for (int i = 0; i < 8; ++i) acc[i] = 0.f;

#define GLD(s) (*(const uint4*)(G + (size_t)(s) * F + foc * 8))
  auto addrow = [&](uint4 q) {
    const __half2* h = (const __half2*)&q;
#pragma unroll
    for (int i = 0; i < 4; ++i) {
      float2 f = __half22float2(h[i]);
      acc[2 * i] += f.x;
      acc[2 * i + 1] += f.y;
    }
  };

  if (eg == 0) addrow(GLD(v));       // self-loop term

  int beg = __builtin_amdgcn_readfirstlane(row_ptr[v]);
  int end = __builtin_amdgcn_readfirstlane(row_ptr[v + 1]);
  int j = beg;
  for (; j + 16 <= end; j += 16) {
    int s0 = ew[j + eg];
    int s1 = ew[j + 8 + eg];
    uint4 a = GLD(s0);
    uint4 b = GLD(s1);
    addrow(a);
    addrow(b);
  }
  if (j + 8 <= end) {
    addrow(GLD(ew[j + eg]));
    j += 8;
  }
  {
    int idx = j + eg;
    if (idx < end) addrow(GLD(ew[idx]));
  }
#undef GLD

#pragma unroll
  for (int m = 8; m <= 32; m <<= 1) {
#pragma unroll
    for (int i = 0; i < 8; ++i) acc[i] += __shfl_xor(acc[i], m);
  }

  if (fok) {
    float dv = dinv[v];
    if constexpr (HOUT) {
      __half* Hout = (__half*)HoutV;
      union { __half2 h2[4]; uint4 u; } cv;
      cv.h2[0] = __floats2half2_rn(fmaxf(dv * acc[0], 0.f), fmaxf(dv * acc[1], 0.f));
      cv.h2[1] = __floats2half2_rn(fmaxf(dv * acc[2], 0.f), fmaxf(dv * acc[3], 0.f));
      cv.h2[2] = __floats2half2_rn(fmaxf(dv * acc[4], 0.f), fmaxf(dv * acc[5], 0.f));
      cv.h2[3] = __floats2half2_rn(fmaxf(dv * acc[6], 0.f), fmaxf(dv * acc[7], 0.f));
      *(uint4*)(Hout + (size_t)v * F + fo * 8) = cv.u;
    } else {
      float* Hout = (float*)HoutV;
      float4 o0, o1;
      o0.x = fmaxf(dv * acc[0], 0.f);
      o0.y = fmaxf(dv * acc[1], 0.f);
      o0.z = fmaxf(dv * acc[2], 0.f);
      o0.w = fmaxf(dv * acc[3], 0.f);
      o1.x = fmaxf(dv * acc[4], 0.f);
      o1.y = fmaxf(dv * acc[5], 0.f);
      o1.z = fmaxf(dv * acc[6], 0.f);
      o1.w = fmaxf(dv * acc[7], 0.f);
      float4* outp = (float4*)(Hout + (size_t)v * F + fo * 8);
      outp[0] = o0;
      outp[1] = o1;
    }
  }
}

extern "C" void kernel_launch(void* const* d_in, const int* in_sizes, int n_in,
                              void* d_out, int out_size, void* d_ws, size_t ws_size,
                              hipStream_t stream) {
  const float* x  = (const float*)d_in[0];
  const int*   eg = (const int*)d_in[1];
  const float* W0 = (const float*)d_in[2];
  const float* W1 = (const float*)d_in[3];
  const float* W2 = (const float*)d_in[4];
  float* out = (float*)d_out;

  const int N = in_sizes[0] / N_FEAT0;  // 100000
  const int E = in_sizes[1] / 2;        // 1600000
  const int* esrc = eg;
  const int* edst = eg + E;
  const int nbuck = (N + BSZ - 1) >> BSH;  // 196

  // workspace layout (256B aligned)
  char* p = (char*)d_ws;
  auto alloc = [&](size_t bytes) {
    char* r = p;
    p += (bytes + 255) & ~(size_t)255;
    return r;
  };
  int*    bfill   = (int*)alloc(256 * 4);
  int*    counts  = (int*)alloc((size_t)N * 4);   // adjacent to bfill: one memset
  int*    row_ptr = (int*)alloc((size_t)(N + 1) * 4);
  float*  dinv    = (float*)alloc((size_t)N * 4);
  int*    ew      = (int*)alloc((size_t)E * 4);
  __half* Wt0     = (__half*)alloc(8192 * 2);
  __half* Wt1     = (__half*)alloc(4096 * 2);
  __half* Wt2     = (__half*)alloc(3072 * 2);
  __half* bufG    = (__half*)alloc((size_t)N * HID * 2);   // 12.8 MB (G1, then G2)
  __half* bufH    = (__half*)alloc((size_t)N * HID * 2);   // 12.8 MB (H1, then H2)
  __half* bufG3   = (__half*)alloc((size_t)N * NCLS * 2);  // 8 MB
  // slab aliases bufH (9.63 MB <= 12.8 MB); hist/perm read it before agg1
  // writes bufH (stream-ordered).
  int* slab = (int*)bufH;

  // zero bfill + counts in one call (contiguous region)
  hipMemsetAsync(bfill, 0, (size_t)((char*)counts - (char*)bfill) + (size_t)N * 4,
                 stream);

  prep_w_kernel<<<60, 256, 0, stream>>>(W0, W1, W2, Wt0, Wt1, Wt2);
  const int sblocks = (E + STILE - 1) / STILE;  // 391
  scatter_kernel<<<sblocks, 256, 0, stream>>>(esrc, edst, bfill, slab, E);
  hist_kernel<<<nbuck * 4, 256, 0, stream>>>(slab, bfill, counts, N);
  scan_kernel<<<nbuck, 512, 0, stream>>>(bfill, counts, row_ptr, dinv, N, nbuck);
  perm_kernel<<<nbuck * 4, 256, 0, stream>>>(slab, bfill, row_ptr, counts, ew, N);

  const int ntiles = (N + 15) / 16;             // 6250
  const int mblocks = (ntiles + 3) / 4;         // 1563
  const int ablocks = (N + 3) / 4;
  // layer 0: 128 -> 64 (f32 x, in-register fp16 cvt, MFMA)
  gemm_mfma<128, 64, true><<<mblocks, 256, 0, stream>>>(x, Wt0, bufG, dinv, N);
  agg_kernel<64, true><<<ablocks, 256, 0, stream>>>(bufG, row_ptr, ew, dinv, bufH, N);
  // layer 1: 64 -> 64 (fp16, MFMA)
  gemm_mfma<64, 64, false><<<mblocks, 256, 0, stream>>>(bufH, Wt1, bufG, dinv, N);
  agg_kernel<64, true><<<ablocks, 256, 0, stream>>>(bufG, row_ptr, ew, dinv, bufH, N);
  // layer 2: 64 -> 40 (fp16, MFMA, Wt2 zero-padded to 48 cols)
  gemm_mfma<64, 40, false><<<mblocks, 256, 0, stream>>>(bufH, Wt2, bufG3, dinv, N);
  agg_kernel<40, false><<<ablocks, 256, 0, stream>>>(bufG3, row_ptr, ew, dinv, out, N);
}

// Round 12
// 300.186 us; speedup vs baseline: 1.1552x; 1.1552x over previous
//
#include <hip/hip_runtime.h>
#include <hip/hip_fp16.h>

#define N_FEAT0 128
#define HID 64
#define NCLS 40

#define BSH 9            // log2 nodes per bucket
#define BSZ 512          // nodes per bucket
#define BCAP 12288       // slab capacity per bucket (mean 8192, sigma ~90 -> 45 sigma margin)
#define STILE 4096       // edges per scatter block (391 blocks)

typedef _Float16 half8 __attribute__((ext_vector_type(8)));
typedef float f32x4 __attribute__((ext_vector_type(4)));

// ---------------- phase 1: LDS-binned scatter of edges into per-bucket slabs ----
// Record = (d & 511) << 17 | s   (s < 2^17 since N = 100000 < 131072).
// Edges register-staged across both passes (no pass-B re-read of 12.8 MB).
__global__ __launch_bounds__(256) void scatter_kernel(const int* __restrict__ esrc,
                                                      const int* __restrict__ edst,
                                                      int* __restrict__ bfill,
                                                      int* __restrict__ slab, int E) {
  __shared__ int cnt[256];
  __shared__ int base[256];
  int t = threadIdx.x;
  int t0 = blockIdx.x * STILE;
  cnt[t] = 0;
  __syncthreads();

  int4 s4[4], d4[4];
  bool ok[4];
  // pass A: load into registers + bucket histogram (E % 4 == 0 -> int4 safe)
#pragma unroll
  for (int i = 0; i < 4; ++i) {
    int e = t0 + i * 1024 + t * 4;
    ok[i] = (e < E);
    if (ok[i]) {
      s4[i] = *(const int4*)(esrc + e);
      d4[i] = *(const int4*)(edst + e);
      atomicAdd(&cnt[d4[i].x >> BSH], 1);
      atomicAdd(&cnt[d4[i].y >> BSH], 1);
      atomicAdd(&cnt[d4[i].z >> BSH], 1);
      atomicAdd(&cnt[d4[i].w >> BSH], 1);
    }
  }
  __syncthreads();
  int c = cnt[t];
  if (c > 0) base[t] = t * BCAP + atomicAdd(&bfill[t], c);
  cnt[t] = 0;
  __syncthreads();

  // pass B: binned emit from registers
#pragma unroll
  for (int i = 0; i < 4; ++i) {
    if (ok[i]) {
#define EMIT(dd, ss)                                             \
      {                                                          \
        int b_ = (dd) >> BSH;                                    \
        int r_ = atomicAdd(&cnt[b_], 1);                         \
        slab[base[b_] + r_] = (((dd) & (BSZ - 1)) << 17) | (ss); \
      }
      EMIT(d4[i].x, s4[i].x)
      EMIT(d4[i].y, s4[i].y)
      EMIT(d4[i].z, s4[i].z)
      EMIT(d4[i].w, s4[i].w)
#undef EMIT
    }
  }
}

// ---------------- phase 2: per-bucket CSR finalize, 1024 threads --------------
// One block per bucket (keeps the scattered 4B ew writes XCD-LOCAL: round-11's
// 4-blocks/bucket split put one bucket's 32KB output window on 4 XCDs ->
// 92.6MB partial-line writebacks, 55us. One L2 owner -> full lines, ~6.4MB).
// 1024 threads: histogram/permute strides halve, 2x writes in flight; the
// 512-entry node scan is a wave-shuffle scan (6 shfl + 2 barriers vs 18).
__global__ __launch_bounds__(1024) void build_kernel(const int* __restrict__ slab,
                                                     const int* __restrict__ bfill,
                                                     int* __restrict__ row_ptr,
                                                     float* __restrict__ dinv,
                                                     int* __restrict__ ew,
                                                     int N, int nbuck) {
  __shared__ int cnt[512];
  __shared__ int pre[512];
  __shared__ int sc[256];
  __shared__ int wsum[8];
  int b = blockIdx.x;
  int t = threadIdx.x;
  int nbase = b << BSH;
  int nNodes = N - nbase;
  if (nNodes > BSZ) nNodes = BSZ;

  // ---- bucket-size scan (threads < 256) -> obase ----
  if (t < 256) sc[t] = (t < nbuck) ? bfill[t] : 0;
  __syncthreads();
  for (int off = 1; off < 256; off <<= 1) {
    int u = 0;
    if (t < 256 && t >= off) u = sc[t - off];
    __syncthreads();
    if (t < 256) sc[t] += u;
    __syncthreads();
  }
  int sz = bfill[b];
  int obase = sc[b] - sz;           // exclusive prefix for this bucket
  if (b == 0 && t == 0) row_ptr[N] = sc[255];  // total == E
  if (t < 512) cnt[t] = 0;
  __syncthreads();

  int sbeg = b * BCAP;

  // per-node histogram (stride 1024)
  for (int r = t; r < sz; r += 1024) atomicAdd(&cnt[((unsigned)slab[sbeg + r]) >> 17], 1);
  __syncthreads();

  // exclusive scan over 512 counters: per-wave shfl scan + 8-partial combine
  int c = 0, incl = 0;
  if (t < 512) {
    c = cnt[t];
    incl = c;
#pragma unroll
    for (int off = 1; off < 64; off <<= 1) {
      int u = __shfl_up(incl, off);
      if ((t & 63) >= off) incl += u;
    }
    if ((t & 63) == 63) wsum[t >> 6] = incl;
  }
  __syncthreads();
  int ex = 0;
  if (t < 512) {
    int w = t >> 6;
    int wpre = 0;
#pragma unroll
    for (int i = 0; i < 7; ++i) wpre += (i < w) ? wsum[i] : 0;
    ex = wpre + incl - c;           // exclusive prefix
  }

  // row_ptr + dinv (coalesced, one node per thread)
  if (t < nNodes) {
    row_ptr[nbase + t] = obase + ex;
    dinv[nbase + t] = rsqrtf((float)(c + 1));
  }
  __syncthreads();
  if (t < 512) {
    pre[t] = ex;
    cnt[t] = 0;
  }
  __syncthreads();

  // final permute: slab (coalesced read, L2-warm) -> node-ordered ew (stride 1024)
  for (int r = t; r < sz; r += 1024) {
    int rec = slab[sbeg + r];
    int dloc = ((unsigned)rec) >> 17;
    int rank = atomicAdd(&cnt[dloc], 1);
    ew[obase + pre[dloc] + rank] = rec & 0x1FFFF;
  }
}

// ---------------- W prep: transpose + fp16-convert the three weight matrices ----
__global__ __launch_bounds__(256) void prep_w_kernel(const float* __restrict__ W0,
                                                     const float* __restrict__ W1,
                                                     const float* __restrict__ W2,
                                                     __half* __restrict__ Wt0,
                                                     __half* __restrict__ Wt1,
                                                     __half* __restrict__ Wt2) {
  int id = blockIdx.x * 256 + threadIdx.x;
  if (id < 8192) {                       // Wt0: 64 x 128
    int c = id >> 7, k = id & 127;
    Wt0[id] = __float2half_rn(W0[k * 64 + c]);
  } else if (id < 8192 + 4096) {         // Wt1: 64 x 64
    int i = id - 8192;
    int c = i >> 6, k = i & 63;
    Wt1[i] = __float2half_rn(W1[k * 64 + c]);
  } else if (id < 8192 + 4096 + 3072) {  // Wt2: 48 x 64 (cols 40..47 zero)
    int i = id - 8192 - 4096;
    int c = i >> 6, k = i & 63;
    Wt2[i] = (c < NCLS) ? __float2half_rn(W2[k * NCLS + c]) : __half(0.f);
  }
}

// ---------------- MFMA GEMM: Out[r][c] = (half) dinv[r] * sum_k A[r][k] W[k][c] --
// v_mfma_f32_16x16x32_f16, verified layouts (guide m89/m91). One wave = one
// 16-row x NC tile; no LDS, no barriers.
template <int K, int NC, bool AF32>
__global__ __launch_bounds__(256) void gemm_mfma(const void* __restrict__ Av,
                                                 const __half* __restrict__ Wt,
                                                 __half* __restrict__ Out,
                                                 const float* __restrict__ dinv,
                                                 int N) {
  constexpr int NT = (NC + 15) / 16;
  int lane = threadIdx.x & 63;
  int r16 = lane & 15;
  int kq = lane >> 4;
  int wid = blockIdx.x * 4 + (threadIdx.x >> 6);
  int ntiles = (N + 15) >> 4;
  if (wid >= ntiles) return;
  int r0 = wid << 4;

  const __half* Ah = (const __half*)Av;
  const float* Af = (const float*)Av;
  int arow = r0 + r16;
  if (arow >= N) arow = N - 1;

  f32x4 acc[NT];
#pragma unroll
  for (int t2 = 0; t2 < NT; ++t2) acc[t2] = (f32x4){0.f, 0.f, 0.f, 0.f};

#pragma unroll
  for (int s = 0; s < K / 32; ++s) {
    half8 a;
    if constexpr (AF32) {
      const float* ap = Af + (size_t)arow * K + s * 32 + kq * 8;
      float4 v0 = *(const float4*)ap;
      float4 v1 = *(const float4*)(ap + 4);
      a[0] = (_Float16)v0.x; a[1] = (_Float16)v0.y;
      a[2] = (_Float16)v0.z; a[3] = (_Float16)v0.w;
      a[4] = (_Float16)v1.x; a[5] = (_Float16)v1.y;
      a[6] = (_Float16)v1.z; a[7] = (_Float16)v1.w;
    } else {
      a = *(const half8*)(Ah + (size_t)arow * K + s * 32 + kq * 8);
    }
#pragma unroll
    for (int t2 = 0; t2 < NT; ++t2) {
      half8 b = *(const half8*)(Wt + (size_t)(t2 * 16 + r16) * K + s * 32 + kq * 8);
      acc[t2] = __builtin_amdgcn_mfma_f32_16x16x32_f16(a, b, acc[t2], 0, 0, 0);
    }
  }

  float4 dv = *(const float4*)(dinv + r0 + kq * 4);
  float ds[4] = {dv.x, dv.y, dv.z, dv.w};
#pragma unroll
  for (int b = 0; b < 4; ++b) {
    int gr = r0 + kq * 4 + b;
#pragma unroll
    for (int t2 = 0; t2 < NT; ++t2) {
      int col = t2 * 16 + r16;
      if (col < NC) Out[(size_t)gr * NC + col] = __float2half_rn(ds[b] * acc[t2][b]);
    }
  }
}

// ---------------- sparse aggregation: one wave per node, fp16 gather ---------
// Row-major G: one edge = one 128B line request (line-rate optimal; round-7
// planar proved line-request count, not bytes, is the wall).
template <int F, bool HOUT>
__global__ __launch_bounds__(256) void agg_kernel(const __half* __restrict__ G,
                                                  const int* __restrict__ row_ptr,
                                                  const int* __restrict__ ew,
                                                  const float* __restrict__ dinv,
                                                  void* __restrict__ HoutV, int N) {
  constexpr int FO = F / 8;
  int gid = blockIdx.x * blockDim.x + threadIdx.x;
  int v = gid >> 6;
  if (v >= N) return;
  int lane = threadIdx.x & 63;
  int eg = lane >> 3;
  int fo = lane & 7;
  bool fok = (fo < FO);
  int foc = fok ? fo : FO - 1;

  float acc[8];
#pragma unroll
  for (int i = 0; i < 8; ++i) acc[i] = 0.f;

#define GLD(s) (*(const uint4*)(G + (size_t)(s) * F + foc * 8))
  auto addrow = [&](uint4 q) {
    const __half2* h = (const __half2*)&q;
#pragma unroll
    for (int i = 0; i < 4; ++i) {
      float2 f = __half22float2(h[i]);
      acc[2 * i] += f.x;
      acc[2 * i + 1] += f.y;
    }
  };

  if (eg == 0) addrow(GLD(v));       // self-loop term

  int beg = __builtin_amdgcn_readfirstlane(row_ptr[v]);
  int end = __builtin_amdgcn_readfirstlane(row_ptr[v + 1]);
  int j = beg;
  for (; j + 16 <= end; j += 16) {
    int s0 = ew[j + eg];
    int s1 = ew[j + 8 + eg];
    uint4 a = GLD(s0);
    uint4 b = GLD(s1);
    addrow(a);
    addrow(b);
  }
  if (j + 8 <= end) {
    addrow(GLD(ew[j + eg]));
    j += 8;
  }
  {
    int idx = j + eg;
    if (idx < end) addrow(GLD(ew[idx]));
  }
#undef GLD

#pragma unroll
  for (int m = 8; m <= 32; m <<= 1) {
#pragma unroll
    for (int i = 0; i < 8; ++i) acc[i] += __shfl_xor(acc[i], m);
  }

  if (fok) {
    float dv = dinv[v];
    if constexpr (HOUT) {
      __half* Hout = (__half*)HoutV;
      union { __half2 h2[4]; uint4 u; } cv;
      cv.h2[0] = __floats2half2_rn(fmaxf(dv * acc[0], 0.f), fmaxf(dv * acc[1], 0.f));
      cv.h2[1] = __floats2half2_rn(fmaxf(dv * acc[2], 0.f), fmaxf(dv * acc[3], 0.f));
      cv.h2[2] = __floats2half2_rn(fmaxf(dv * acc[4], 0.f), fmaxf(dv * acc[5], 0.f));
      cv.h2[3] = __floats2half2_rn(fmaxf(dv * acc[6], 0.f), fmaxf(dv * acc[7], 0.f));
      *(uint4*)(Hout + (size_t)v * F + fo * 8) = cv.u;
    } else {
      float* Hout = (float*)HoutV;
      float4 o0, o1;
      o0.x = fmaxf(dv * acc[0], 0.f);
      o0.y = fmaxf(dv * acc[1], 0.f);
      o0.z = fmaxf(dv * acc[2], 0.f);
      o0.w = fmaxf(dv * acc[3], 0.f);
      o1.x = fmaxf(dv * acc[4], 0.f);
      o1.y = fmaxf(dv * acc[5], 0.f);
      o1.z = fmaxf(dv * acc[6], 0.f);
      o1.w = fmaxf(dv * acc[7], 0.f);
      float4* outp = (float4*)(Hout + (size_t)v * F + fo * 8);
      outp[0] = o0;
      outp[1] = o1;
    }
  }
}

extern "C" void kernel_launch(void* const* d_in, const int* in_sizes, int n_in,
                              void* d_out, int out_size, void* d_ws, size_t ws_size,
                              hipStream_t stream) {
  const float* x  = (const float*)d_in[0];
  const int*   eg = (const int*)d_in[1];
  const float* W0 = (const float*)d_in[2];
  const float* W1 = (const float*)d_in[3];
  const float* W2 = (const float*)d_in[4];
  float* out = (float*)d_out;

  const int N = in_sizes[0] / N_FEAT0;  // 100000
  const int E = in_sizes[1] / 2;        // 1600000
  const int* esrc = eg;
  const int* edst = eg + E;
  const int nbuck = (N + BSZ - 1) >> BSH;  // 196

  // workspace layout (256B aligned)
  char* p = (char*)d_ws;
  auto alloc = [&](size_t bytes) {
    char* r = p;
    p += (bytes + 255) & ~(size_t)255;
    return r;
  };
  int*    bfill   = (int*)alloc(256 * 4);
  int*    row_ptr = (int*)alloc((size_t)(N + 1) * 4);
  float*  dinv    = (float*)alloc((size_t)N * 4);
  int*    ew      = (int*)alloc((size_t)E * 4);
  __half* Wt0     = (__half*)alloc(8192 * 2);
  __half* Wt1     = (__half*)alloc(4096 * 2);
  __half* Wt2     = (__half*)alloc(3072 * 2);
  __half* bufG    = (__half*)alloc((size_t)N * HID * 2);   // 12.8 MB (G1, then G2)
  __half* bufH    = (__half*)alloc((size_t)N * HID * 2);   // 12.8 MB (H1, then H2)
  __half* bufG3   = (__half*)alloc((size_t)N * NCLS * 2);  // 8 MB
  // slab aliases bufH (9.63 MB <= 12.8 MB); build reads it before agg1 writes
  // bufH (stream-ordered).
  int* slab = (int*)bufH;

  hipMemsetAsync(bfill, 0, 256 * 4, stream);

  prep_w_kernel<<<60, 256, 0, stream>>>(W0, W1, W2, Wt0, Wt1, Wt2);
  const int sblocks = (E + STILE - 1) / STILE;  // 391
  scatter_kernel<<<sblocks, 256, 0, stream>>>(esrc, edst, bfill, slab, E);
  build_kernel<<<nbuck, 1024, 0, stream>>>(slab, bfill, row_ptr, dinv, ew, N, nbuck);

  const int ntiles = (N + 15) / 16;             // 6250
  const int mblocks = (ntiles + 3) / 4;         // 1563
  const int ablocks = (N + 3) / 4;
  // layer 0: 128 -> 64 (f32 x, in-register fp16 cvt, MFMA)
  gemm_mfma<128, 64, true><<<mblocks, 256, 0, stream>>>(x, Wt0, bufG, dinv, N);
  agg_kernel<64, true><<<ablocks, 256, 0, stream>>>(bufG, row_ptr, ew, dinv, bufH, N);
  // layer 1: 64 -> 64 (fp16, MFMA)
  gemm_mfma<64, 64, false><<<mblocks, 256, 0, stream>>>(bufH, Wt1, bufG, dinv, N);
  agg_kernel<64, true><<<ablocks, 256, 0, stream>>>(bufG, row_ptr, ew, dinv, bufH, N);
  // layer 2: 64 -> 40 (fp16, MFMA, Wt2 zero-padded to 48 cols)
  gemm_mfma<64, 40, false><<<mblocks, 256, 0, stream>>>(bufH, Wt2, bufG3, dinv, N);
  agg_kernel<40, false><<<ablocks, 256, 0, stream>>>(bufG3, row_ptr, ew, dinv, out, N);
}